// Round 6
// baseline (107.473 us; speedup 1.0000x reference)
//
#include <hip/hip_runtime.h>
#include <hip/hip_bf16.h>

// USM sharpen, 48 images of 512x512 f32, 51-tap separable Gaussian, reflect pad.
// 4 passes, each: column-major bf16 LDS stage + per-thread register sliding
// window along the slow dim (VB=16) + f32 LDS transpose tile for coalesced
// transposed output with fused elementwise epilogue.
//   pass1: img  f32[y][x] --vblur--> vb  bf16[x][y]
//   pass2: vb  bf16[x][y] --xblur--> res bf16[y][x] = img - blur
//   pass3: res bf16[y][x] --mask+vblur--> vb bf16[x][y]
//   pass4: vb  bf16[x][y] --xblur--> out f32[y][x] = img + sm*(sharp-img)
// Key change vs round 5: stage is COLUMN-major bf16 with an XOR swizzle so the
// 66 sliding-window taps are read as 17 ds_read_b64 (4 taps each) instead of
// 66 ds_read_b32 -- the LDS pipe was a ~14 us/pass co-bottleneck. LDS union
// shrinks 45.6 -> 33 KB => 4 blocks/CU (32 waves, full occupancy).

constexpr int IMG = 512;
constexpr int NIMG = 48;
constexpr int K = 51, P = 25;
constexpr int CB = 64;              // columns per block (= lanes)
constexpr int RB = 128;             // output rows per block
constexpr int WAVES = 8;            // 512 threads
constexpr int VB = 16;              // rows per thread (proven unrollable; 32 spills)
constexpr int NLOOP = VB + K - 1;   // 66 taps window
constexpr int NCHUNK = 17;          // ceil-cover of 66 rows in 4-row b64 chunks
constexpr int TR = RB + 2 * P;      // 178 staged rows
constexpr int SROW = 256;           // padded row space per column (swizzle-safe)
constexpr int TRS = RB + 1;         // transpose stride 129 -> (lane+row)%32, free
constexpr int LDS_BYTES = CB * TRS * 4;  // 33024 >= stage CB*SROW*2 = 32768

__device__ __forceinline__ float bf2f(unsigned short u) {
    unsigned int x = (unsigned int)u << 16;
    return __builtin_bit_cast(float, x);
}
__device__ __forceinline__ unsigned short f2bf(float f) {
    unsigned int u = __builtin_bit_cast(unsigned int, f);
    u += 0x7FFF + ((u >> 16) & 1);  // RNE (finite inputs only)
    return (unsigned short)(u >> 16);
}

// stage element index: column-major, rows XOR-swizzled (bits >=2 only, so
// 4-row aligned chunks stay contiguous and 8B-aligned)
__device__ __forceinline__ int sidx(int c, int r) {
    return c * SROW + (r ^ ((c & 15) << 2));
}

// SRCB: src element type 0=f32, 1=bf16
// LOADM: 1 = apply mask(|v|*255 > 10) at stage time (bf16 src only)
// STOREM: 0 = blur -> dst bf16 (transposed)
//         1 = img - blur -> dst bf16 (residual)
//         2 = sm=blur; dst f32 = img + sm*(clip(img+0.5*res,0,1) - img)
template <int SRCB, int LOADM, int STOREM>
__global__ __launch_bounds__(512) void pass_kern(const void* __restrict__ srcv,
                                                 const float* __restrict__ img,
                                                 const unsigned short* __restrict__ res,
                                                 void* __restrict__ dstv,
                                                 const float* __restrict__ k1d) {
    __shared__ unsigned char ldsraw[LDS_BYTES];  // union: bf16 stage / f32 transpose
    unsigned short* st = (unsigned short*)ldsraw;
    float* tr = (float*)ldsraw;

    const int lane = threadIdx.x & 63;
    const int wvu = __builtin_amdgcn_readfirstlane(threadIdx.x >> 6);  // scalarize
    const int c0 = blockIdx.x * CB;
    const int r0 = blockIdx.y * RB;
    const size_t base = (size_t)blockIdx.z * (IMG * IMG);

    // ---- stage 178 reflect-padded rows, column-major bf16, swizzled ----
    for (int r = wvu; r < TR; r += WAVES) {
        int y = r0 - P + r;                  // wave-uniform -> SALU
        const int ya = y < 0 ? -y : y;
        y = min(ya, 2 * IMG - 2 - y);        // reflect; identity in interior
        const size_t si = base + (size_t)y * IMG + c0 + lane;
        unsigned short u;
        if (SRCB) {
            u = ((const unsigned short*)srcv)[si];
            if (LOADM == 1) {
                const float v = bf2f(u);
                u = (fabsf(v) * 255.0f > 10.0f) ? 0x3F80 : 0;  // 1.0bf16 : 0
            }
        } else {
            u = f2bf(((const float*)srcv)[si]);
        }
        st[sidx(lane, r)] = u;
    }

    float kern[K];
#pragma unroll
    for (int k = 0; k < K; ++k) kern[k] = k1d[k];  // uniform -> scalar regs

    __syncthreads();

    // ---- register sliding window: 17 x ds_read_b64 (4 bf16 taps each) ----
    float acc[VB];
#pragma unroll
    for (int o = 0; o < VB; ++o) acc[o] = 0.f;

    const int trow0 = wvu * VB;                // multiple of 16
    const int sbase = lane * SROW;
    const int sx = (lane & 15) << 2;
#pragma unroll
    for (int t = 0; t < NCHUNK; ++t) {
        const int rb4 = trow0 + 4 * t;         // multiple of 4
        const uint2 ch = *(const uint2*)(&st[sbase + (rb4 ^ sx)]);  // ds_read_b64
#pragma unroll
        for (int i = 0; i < 4; ++i) {
            const int r = 4 * t + i;
            if (r < NLOOP) {
                const unsigned short uu =
                    (i == 0) ? (unsigned short)ch.x :
                    (i == 1) ? (unsigned short)(ch.x >> 16) :
                    (i == 2) ? (unsigned short)ch.y :
                               (unsigned short)(ch.y >> 16);
                const float v = bf2f(uu);
#pragma unroll
                for (int o = 0; o < VB; ++o) {
                    const int k = r - o;
                    if (0 <= k && k < K) acc[o] = fmaf(kern[k], v, acc[o]);
                }
            }
        }
    }

    __syncthreads();  // stage fully consumed; safe to overwrite (union)

    // ---- transpose tile: write addr = lane*129 + row -> (lane+row)%32, free ----
#pragma unroll
    for (int o = 0; o < VB; ++o) tr[lane * TRS + trow0 + o] = acc[o];
    __syncthreads();

    // ---- transposed coalesced store + fused epilogue ----
#pragma unroll
    for (int i = 0; i < 8; ++i) {
        const int cc = wvu * 8 + i;
#pragma unroll
        for (int j = 0; j < 2; ++j) {
            const int rr = j * 64 + lane;
            const float bv = tr[cc * TRS + rr];
            const size_t di = base + (size_t)(c0 + cc) * IMG + (r0 + rr);
            if (STOREM == 0) {
                ((unsigned short*)dstv)[di] = f2bf(bv);
            } else if (STOREM == 1) {
                ((unsigned short*)dstv)[di] = f2bf(img[di] - bv);
            } else {
                const float iv = img[di];
                const float rv = bf2f(res[di]);
                float sharp = fmaf(0.5f, rv, iv);
                sharp = fminf(fmaxf(sharp, 0.f), 1.f);
                ((float*)dstv)[di] = fmaf(bv, sharp - iv, iv);  // img + sm*(sharp-img)
            }
        }
    }
}

extern "C" void kernel_launch(void* const* d_in, const int* in_sizes, int n_in,
                              void* d_out, int out_size, void* d_ws, size_t ws_size,
                              hipStream_t stream) {
    (void)in_sizes; (void)n_in; (void)out_size; (void)ws_size;
    const float* img = (const float*)d_in[0];
    const float* k1d = (const float*)d_in[1];
    float* out = (float*)d_out;
    unsigned short* vb = (unsigned short*)d_ws;                             // 25165824 B
    unsigned short* rs = (unsigned short*)d_ws + (size_t)NIMG * IMG * IMG;  // 25165824 B

    const dim3 grid(IMG / CB, IMG / RB, NIMG);  // (8, 4, 48) = 1536 blocks

    pass_kern<0, 0, 0><<<grid, 512, 0, stream>>>(img, nullptr, nullptr, vb, k1d);
    pass_kern<1, 0, 1><<<grid, 512, 0, stream>>>(vb, img, nullptr, rs, k1d);   // rs = residual
    pass_kern<1, 1, 0><<<grid, 512, 0, stream>>>(rs, nullptr, nullptr, vb, k1d);
    pass_kern<1, 0, 2><<<grid, 512, 0, stream>>>(vb, img, rs, out, k1d);       // final
}

// Round 7
// 102.492 us; speedup vs baseline: 1.0486x; 1.0486x over previous
//
#include <hip/hip_runtime.h>
#include <hip/hip_bf16.h>

// USM sharpen via MFMA: the 51-tap 1D conv along the slow dim is a 16x96
// band-matrix multiply  out[y0+i][x] = sum_r W[i][r] * in[y0-25+r][x],
// W[i][r] = kern[r-i], executed as 3x mfma_f32_16x16x32_bf16 per 16x16 tile.
// 4 passes (vblur -> hblur+res -> mask+vblur -> hblur+final), each pass:
//   stage: column-major bf16 tile [64 cols][208 rows] in LDS, XOR-swizzled
//          at 16B granularity (conflict-free b128 both sides), rows 178..207
//          zero-filled so the W zero-pad region never touches garbage.
//   compute: per wave 4 tiles x 3 MFMA; A-frags from an LDS-built W band.
//   store: C-frag rows are 4 consecutive slow-coords -> packed transposed
//          stores direct from registers (no transpose tile, one barrier).
// Layout safety: A and B fragments are indexed with the SAME (lane>>4, j)->k
// function, so any hardware within-group k-permutation cancels in the
// contraction. C/D layout is the m89-verified col=lane&15,row=(lane>>4)*4+q.
//   pass1: img  f32[y][x] --vblur--> vb  bf16[x][y]
//   pass2: vb  bf16[x][y] --xblur--> res bf16[y][x] = img - blur
//   pass3: res bf16[y][x] --mask+vblur--> vb bf16[x][y]
//   pass4: vb  bf16[x][y] --xblur--> out f32[y][x] = img + sm*(sharp-img)

typedef __attribute__((ext_vector_type(8))) short bf16x8;
typedef __attribute__((ext_vector_type(4))) float f32x4;

constexpr int IMG = 512, NIMG = 48, K = 51, P = 25;
constexpr int CB = 64;      // fast-dim cols per block (= lanes)
constexpr int RB = 128;     // slow-dim output rows per block
constexpr int WAVES = 8;    // 512 threads
constexpr int TR = RB + 2 * P;  // 178 data rows staged
constexpr int SCH = 26;         // 8-row stage chunks (208 rows incl. zero tail)
constexpr int SROW = 256;       // row space per column (swizzle-safe)
constexpr int NK = 96;          // band width padded to 3 x K=32

__device__ __forceinline__ float bf2f(unsigned short u) {
    return __builtin_bit_cast(float, (unsigned)u << 16);
}
__device__ __forceinline__ unsigned short f2bf(float f) {
    unsigned u = __builtin_bit_cast(unsigned, f);
    u += 0x7FFF + ((u >> 16) & 1);  // RNE, finite inputs only
    return (unsigned short)(u >> 16);
}
// column-major stage index; XOR swizzle flips s bits 3..5 (16B granularity:
// 8-short chunks stay contiguous & aligned; spreads cols over all 32 banks)
__device__ __forceinline__ int sidx(int c, int s) {
    return c * SROW + (s ^ ((c & 7) << 3));
}

// SRCB: src 0=f32, 1=bf16.  LOADM 1: mask(|v|*255>10) at stage time.
// STOREM: 0 = blur->bf16 dst; 1 = img-blur->bf16 dst; 2 = final f32 dst.
template <int SRCB, int LOADM, int STOREM>
__global__ __launch_bounds__(512, 8) void pass_kern(const void* __restrict__ srcv,
                                                    const float* __restrict__ img,
                                                    const unsigned short* __restrict__ res,
                                                    void* __restrict__ dstv,
                                                    const float* __restrict__ k1d) {
    __shared__ unsigned short st[CB * SROW];  // 32 KB staged tile
    __shared__ unsigned short wb[16 * NK];    // 3 KB band matrix W
    const int tid = threadIdx.x, lane = tid & 63;
    const int wv = __builtin_amdgcn_readfirstlane(tid >> 6);
    const int c0 = blockIdx.x * CB;
    const int r0 = blockIdx.y * RB;
    const size_t base = (size_t)blockIdx.z * (IMG * IMG);

    // ---- build W[i][r] = kern[r-i] (16 x 96, bf16) ----
#pragma unroll
    for (int e = 0; e < 3; ++e) {
        const int idx = tid + e * 512;          // 1536 = 3*512 exactly
        const int i = idx / NK, r = idx - i * NK;
        const int t = r - i;
        wb[idx] = (t >= 0 && t < K) ? f2bf(k1d[t]) : (unsigned short)0;
    }

    // ---- stage: column-major bf16, swizzled, zero tail (rows 178..207) ----
    for (int ch = wv; ch < SCH; ch += WAVES) {
        const int s0 = ch * 8;
        unsigned pk[4];
#pragma unroll
        for (int j2 = 0; j2 < 4; ++j2) {
            unsigned short uu[2];
#pragma unroll
            for (int h = 0; h < 2; ++h) {
                const int s = s0 + j2 * 2 + h;   // wave-uniform
                unsigned short u = 0;
                if (s < TR) {
                    int y = r0 - P + s;
                    const int ya = y < 0 ? -y : y;
                    y = min(ya, 2 * IMG - 2 - y);     // reflect
                    const size_t si = base + (size_t)y * IMG + c0 + lane;
                    if (SRCB) {
                        u = ((const unsigned short*)srcv)[si];
                        if (LOADM == 1) u = (fabsf(bf2f(u)) * 255.0f > 10.0f) ? 0x3F80 : 0;
                    } else {
                        u = f2bf(((const float*)srcv)[si]);
                    }
                }
                uu[h] = u;
            }
            pk[j2] = (unsigned)uu[0] | ((unsigned)uu[1] << 16);
        }
        *(uint4*)&st[sidx(lane, s0)] = make_uint4(pk[0], pk[1], pk[2], pk[3]);  // b128
    }
    __syncthreads();

    // ---- compute: per wave, 4 tiles of 16x16, 3 MFMA each ----
    const int m = lane & 15, g = lane >> 4;
    bf16x8 afr[3];
#pragma unroll
    for (int rs = 0; rs < 3; ++rs)
        afr[rs] = *(const bf16x8*)&wb[m * NK + rs * 32 + g * 8];

    const int y0 = wv * 16;  // wave's slow-dim tile offset in block
#pragma unroll
    for (int ct = 0; ct < 4; ++ct) {
        const int c = ct * 16 + m;
        f32x4 acc = {0.f, 0.f, 0.f, 0.f};
#pragma unroll
        for (int rs = 0; rs < 3; ++rs) {
            const bf16x8 bfr = *(const bf16x8*)&st[sidx(c, y0 + rs * 32 + g * 8)];
            acc = __builtin_amdgcn_mfma_f32_16x16x32_bf16(afr[rs], bfr, acc, 0, 0, 0);
        }
        // C/D: col = lane&15 (fast dim), rows = y0 + g*4 + q (4 consecutive)
        const int Cg = c0 + c;
        const int Rg = r0 + y0 + g * 4;
        const size_t di = base + (size_t)Cg * IMG + Rg;  // transposed store
        if (STOREM == 0) {
            const unsigned d0 = (unsigned)f2bf(acc[0]) | ((unsigned)f2bf(acc[1]) << 16);
            const unsigned d1 = (unsigned)f2bf(acc[2]) | ((unsigned)f2bf(acc[3]) << 16);
            *(uint2*)&((unsigned short*)dstv)[di] = make_uint2(d0, d1);
        } else if (STOREM == 1) {
            const f32x4 iv = *(const f32x4*)&img[di];
            const unsigned d0 = (unsigned)f2bf(iv[0] - acc[0]) | ((unsigned)f2bf(iv[1] - acc[1]) << 16);
            const unsigned d1 = (unsigned)f2bf(iv[2] - acc[2]) | ((unsigned)f2bf(iv[3] - acc[3]) << 16);
            *(uint2*)&((unsigned short*)dstv)[di] = make_uint2(d0, d1);
        } else {
            const f32x4 iv = *(const f32x4*)&img[di];
            const uint2 rv2 = *(const uint2*)&res[di];
            f32x4 o;
#pragma unroll
            for (int q = 0; q < 4; ++q) {
                const unsigned rw = (q < 2) ? rv2.x : rv2.y;
                const float rvq = bf2f((unsigned short)(rw >> ((q & 1) * 16)));
                float sharp = fmaf(0.5f, rvq, iv[q]);
                sharp = fminf(fmaxf(sharp, 0.f), 1.f);
                o[q] = fmaf(acc[q], sharp - iv[q], iv[q]);  // img + sm*(sharp-img)
            }
            *(f32x4*)&((float*)dstv)[di] = o;
        }
    }
}

extern "C" void kernel_launch(void* const* d_in, const int* in_sizes, int n_in,
                              void* d_out, int out_size, void* d_ws, size_t ws_size,
                              hipStream_t stream) {
    (void)in_sizes; (void)n_in; (void)out_size; (void)ws_size;
    const float* img = (const float*)d_in[0];
    const float* k1d = (const float*)d_in[1];
    float* out = (float*)d_out;
    unsigned short* vb = (unsigned short*)d_ws;                             // 25165824 B
    unsigned short* rs = (unsigned short*)d_ws + (size_t)NIMG * IMG * IMG;  // 25165824 B

    const dim3 grid(IMG / CB, IMG / RB, NIMG);  // (8, 4, 48) = 1536 blocks

    pass_kern<0, 0, 0><<<grid, 512, 0, stream>>>(img, nullptr, nullptr, vb, k1d);
    pass_kern<1, 0, 1><<<grid, 512, 0, stream>>>(vb, img, nullptr, rs, k1d);   // rs = residual
    pass_kern<1, 1, 0><<<grid, 512, 0, stream>>>(rs, nullptr, nullptr, vb, k1d);
    pass_kern<1, 0, 2><<<grid, 512, 0, stream>>>(vb, img, rs, out, k1d);       // final
}